// Round 16
// baseline (149.714 us; speedup 1.0000x reference)
//
#include <hip/hip_runtime.h>

// QKV attention, N=4 H=8 C=64 T=2048, fp32 in/out, bf16 MFMA internally.
// R16: R12 base (best: 58.3us; R15's V-fold reverted — it moved cost from
// prep into the attn convoy window) + bank-conflict fix. R12's 2^22 conflict
// cycles are the staging ds_writes: addr = sr*128B + sp*16B -> bank window
// 4*sp, 8 lanes/window = 2x the b128 minimum. Fix: pad LDS row stride to 68
// elements (136B = 34 banks) -> rows shift banks by 2; writes land at the
// 8/bank minimum, reads at 4/bank minimum (R5/R6 measured ZERO conflicts at
// STR=68). XOR swizzle removed entirely (staging source now linear).
// LDS 64 -> 68KB (2 blocks x 68KB = 136KB < 160KB/CU, occupancy unchanged).

typedef __bf16 bf8v __attribute__((ext_vector_type(8)));
typedef float f16v __attribute__((ext_vector_type(16)));
typedef int i4 __attribute__((ext_vector_type(4)));

#define SEQ 2048
#define DD 64
#define NHEADS 32
#define QBLK 128
#define SBLK 64
#define NTILES 32             // s-tiles total; 16 per s-group
#define TILEK (SBLK * DD)     // elements per K/V source tile (4096)
#define STR 68                // padded LDS row stride in bf16 (136 B)
#define TILEE (SBLK * STR)    // elements per padded LDS tile (4352 = 8704 B)
#define NTHR 512

// scale = 1/sqrt(sqrt(64)) on both q and k; log2(e) folded into q's side
#define KSC 0.35355339059327373f
#define QSC (0.35355339059327373f * 1.4426950408889634f)

#if __has_builtin(__builtin_amdgcn_exp2f)
#define EXP2(x) __builtin_amdgcn_exp2f(x)
#else
#define EXP2(x) exp2f(x)
#endif

__device__ __forceinline__ void gload16(i4& dst, const void* p) {
    asm volatile("global_load_dwordx4 %0, %1, off" : "=&v"(dst) : "v"(p));
}

#define SBAR() __builtin_amdgcn_sched_barrier(0)
// drain-all: correct regardless of compiler-inserted vmem ops (spill-safe)
#define VMWAIT0() do { asm volatile("s_waitcnt vmcnt(0)" ::: "memory"); SBAR(); } while (0)

// packed f32->bf16 convert (T12 recipe, learn_hip-verified)
__device__ __forceinline__ unsigned cvtpk(float a, float b) {
    unsigned r;
    asm("v_cvt_pk_bf16_f32 %0, %1, %2" : "=v"(r) : "v"(a), "v"(b));
    return r;
}

// hi-half lane exchange (verified R8): a = {a_lo, b_lo'}, b = {a_hi', b_hi}
#if __has_builtin(__builtin_amdgcn_permlane32_swap)
typedef int i2v __attribute__((ext_vector_type(2)));
__device__ __forceinline__ void plswap(unsigned& a, unsigned& b) {
    i2v r = __builtin_amdgcn_permlane32_swap((int)a, (int)b, false, false);
    a = (unsigned)r.x;
    b = (unsigned)r.y;
}
#else
__device__ __forceinline__ void plswap(unsigned& a, unsigned& b) {
    asm volatile("v_permlane32_swap_b32 %0, %1" : "+v"(a), "+v"(b));
}
#endif

// ---------------- prep: fp32 -> bf16, K transposed+scaled, V straight --------
__global__ void prep_kernel(const float* __restrict__ qkv,
                            __bf16* __restrict__ KT, __bf16* __restrict__ Vb) {
    const int bx = blockIdx.x, tid = threadIdx.x;
    if (bx < 256) {
        const int head = bx >> 3, sblk = bx & 7;
        const int b = head >> 3, h = head & 7;
        const float* kp = qkv + (size_t)(b * 1536 + 512 + h * 64) * SEQ;
        __bf16* dst = KT + (size_t)head * SEQ * DD;
        const int s = sblk * 256 + tid;
#pragma unroll
        for (int c0 = 0; c0 < DD; c0 += 8) {
            bf8v v;
#pragma unroll
            for (int j = 0; j < 8; ++j)
                v[j] = (__bf16)(kp[(size_t)(c0 + j) * SEQ + s] * KSC);
            *(bf8v*)(dst + (size_t)s * DD + c0) = v;
        }
    } else {
        const int job = bx - 256;
        const int head = job >> 4, part = job & 15;
        const int b = head >> 3, h = head & 7;
        const float* vp = qkv + (size_t)(b * 1536 + 1024 + h * 64) * SEQ;
        __bf16* dst = Vb + (size_t)head * DD * SEQ;
#pragma unroll
        for (int i = 0; i < 4; ++i) {
            const int e = part * 8192 + (i * 256 + tid) * 8;
            const float4* f = (const float4*)(vp + e);
            float4 a = f[0], c = f[1];
            bf8v o;
            o[0] = (__bf16)a.x; o[1] = (__bf16)a.y; o[2] = (__bf16)a.z; o[3] = (__bf16)a.w;
            o[4] = (__bf16)c.x; o[5] = (__bf16)c.y; o[6] = (__bf16)c.z; o[7] = (__bf16)c.w;
            *(bf8v*)(dst + e) = o;
        }
    }
}

// padded LDS fragment read: row r (stride STR elem = 136 B), 16B chunk c16
__device__ __forceinline__ bf8v ldpad(const __bf16* base, int r, int c16) {
    return *(const bf8v*)(base + r * STR + ((c16) << 3));
}

__global__ __launch_bounds__(NTHR, 4) void attn_kernel(
    const float* __restrict__ qkv, const __bf16* __restrict__ KT,
    const __bf16* __restrict__ Vb, float* __restrict__ out)
{
    // 68KB pool: padded K/V tiles (2 grp x dbuf x 8704B x2); combine overlays.
    __shared__ __align__(16) char pool[4 * TILEE * 2 * 2];   // 69632 B
    __bf16* KLg = (__bf16*)pool;                       // [grp*2+buf][TILEE]
    __bf16* VLg = (__bf16*)(pool + 4 * TILEE * 2);     // [grp*2+buf][TILEE]
    float* comb  = (float*)pool;                       // [128][65] fp32 overlay
    float* combl = (float*)(pool + 33280);             // [128] fp32

    const int tid = threadIdx.x;
    const int wid = tid >> 6;
    const int gg  = wid >> 2;          // s-group 0/1
    const int qw  = wid & 3;           // q-wave within group
    const int lane = tid & 63;
    const int hi = lane >> 5;
    const int l31 = lane & 31;

    // XCD-bijective swizzle: 512 blocks, 8 XCDs -> 64-block chunks = 4 heads/XCD
    const int bid = blockIdx.x;
    const int bx = (bid & 7) * 64 + (bid >> 3);
    const int head = bx >> 4;
    const int t0 = (bx & 15) * QBLK;
    const int b = head >> 3, h = head & 7;

    const float* qp = qkv + (size_t)(b * 1536 + h * 64) * SEQ;
    const __bf16* kt = KT + (size_t)head * SEQ * DD;
    const __bf16* vb = Vb + (size_t)head * DD * SEQ;
    float* op = out + (size_t)head * DD * SEQ;

    // ---- staging geometry (per s-group: 256 threads cover the 64-row tile) --
    // linear source chunk (no swizzle); padded LDS dest row stride STR
    const int g256 = tid & 255;
    const int sp  = g256 & 7;          // 16B-chunk position within row
    const int sr  = g256 >> 3;         // 0..31
    const __bf16* kg0 = kt + sr * DD + (sp << 3);
    const __bf16* kg1 = kt + (sr + 32) * DD + (sp << 3);
    const __bf16* vg0 = vb + (size_t)sr * SEQ + (sp << 3);
    const __bf16* vg1 = vb + (size_t)(sr + 32) * SEQ + (sp << 3);
    const int l0 = sr * STR + (sp << 3);
    const int l1 = (sr + 32) * STR + (sp << 3);

    i4 rk0, rk1, rv0, rv1;

    // ---- prologue: issue group's tile(gg) loads; Q convert overlaps flight --
    SBAR();
    gload16(rk0, kg0 + gg * TILEK);
    gload16(rk1, kg1 + gg * TILEK);
    gload16(rv0, vg0 + gg * SBLK);
    gload16(rv1, vg1 + gg * SBLK);
    SBAR();

    // Q B-fragments for 32x32x16: col = t = l31, k = c = kb*16 + hi*8 + j
    const int tq = t0 + qw * 32 + l31;
    bf8v qf[4];
#pragma unroll
    for (int kb = 0; kb < 4; ++kb) {
        bf8v q;
#pragma unroll
        for (int j = 0; j < 8; ++j)
            q[j] = (__bf16)(qp[(size_t)(kb * 16 + hi * 8 + j) * SEQ + tq] * QSC);
        qf[kb] = q;
    }

    f16v Oacc[2];
    Oacc[0] = (f16v)0.0f;
    Oacc[1] = (f16v)0.0f;
    float lp[4] = {0.f, 0.f, 0.f, 0.f};

    VMWAIT0();
    {
        __bf16* k0 = KLg + (2 * gg) * TILEE;
        __bf16* v0 = VLg + (2 * gg) * TILEE;
        *(i4*)&k0[l0] = rk0;  *(i4*)&k0[l1] = rk1;
        *(i4*)&v0[l0] = rv0;  *(i4*)&v0[l1] = rv1;
    }
    __syncthreads();

    // ---- main loop: 16 iterations, group gg computes tiles 2*it+gg ----
    for (int it = 0; it < NTILES / 2; ++it) {
        const int cb = it & 1;
        const __bf16* kcu = KLg + (2 * gg + cb) * TILEE;
        const __bf16* vcu = VLg + (2 * gg + cb) * TILEE;
        const bool more = (it + 1 < NTILES / 2);

        // pinned issue of the group's next tile; latency hides under compute
        if (more) {
            const int tg = 2 * (it + 1) + gg;
            SBAR();
            gload16(rk0, kg0 + tg * TILEK);
            gload16(rk1, kg1 + tg * TILEK);
            gload16(rv0, vg0 + tg * SBLK);
            gload16(rv1, vg1 + tg * SBLK);
            SBAR();
        }

        // ---- QK^T + softmax, sequential over sb (caps live regs: one S) ----
        // S^T rows s = sb*32 + (reg&3) + 8*(reg>>2) + 4*hi, col t = l31
        unsigned pd[2][4][2];
#pragma unroll
        for (int sb = 0; sb < 2; ++sb) {
            f16v S = (f16v)0.0f;
            __builtin_amdgcn_s_setprio(1);
#pragma unroll
            for (int kb = 0; kb < 4; ++kb) {
                bf8v a = ldpad(kcu, sb * 32 + l31, 2 * kb + hi);
                S = __builtin_amdgcn_mfma_f32_32x32x16_bf16(a, qf[kb], S, 0, 0, 0);
            }
            __builtin_amdgcn_s_setprio(0);

            // exps via hazard-safe builtin; sums in f32; bf16 pack via cvt_pk
#pragma unroll
            for (int q = 0; q < 4; ++q) {
                float e0 = EXP2(S[4 * q + 0]);
                float e1 = EXP2(S[4 * q + 1]);
                float e2 = EXP2(S[4 * q + 2]);
                float e3 = EXP2(S[4 * q + 3]);
                lp[q] += (e0 + e1) + (e2 + e3);
                pd[sb][q][0] = cvtpk(e0, e1);
                pd[sb][q][1] = cvtpk(e2, e3);
            }
        }

        // hi-half exchange -> complete PV B-frags in-register
#pragma unroll
        for (int sb = 0; sb < 2; ++sb)
#pragma unroll
            for (int m = 0; m < 2; ++m) {
                plswap(pd[sb][2 * m][0], pd[sb][2 * m + 1][0]);
                plswap(pd[sb][2 * m][1], pd[sb][2 * m + 1][1]);
            }

        // ---- mid-iteration sync: land next tile, publish to buf^1, barrier --
        if (more) {
            VMWAIT0();
            __bf16* kn = KLg + (2 * gg + (cb ^ 1)) * TILEE;
            __bf16* vn = VLg + (2 * gg + (cb ^ 1)) * TILEE;
            *(i4*)&kn[l0] = rk0;  *(i4*)&kn[l1] = rk1;
            *(i4*)&vn[l0] = rv0;  *(i4*)&vn[l1] = rv1;
            __syncthreads();
        }

        // VALU(permlane)->MFMA-read hazard guard for the no-barrier last iter
        asm volatile("s_nop 2" :::);

        // ---- PV: O[c][t] += V[c][s] P^T[s][t]; V frags loaded per-kb ----
        __builtin_amdgcn_s_setprio(1);
#pragma unroll
        for (int sb = 0; sb < 2; ++sb)
#pragma unroll
            for (int m = 0; m < 2; ++m) {
                const int kb = 2 * sb + m;
                union { unsigned u[4]; bf8v b; } f;
                f.u[0] = pd[sb][2 * m][0];
                f.u[1] = pd[sb][2 * m][1];
                f.u[2] = pd[sb][2 * m + 1][0];
                f.u[3] = pd[sb][2 * m + 1][1];
                bf8v v0 = ldpad(vcu, l31,      2 * kb + hi);
                bf8v v1 = ldpad(vcu, 32 + l31, 2 * kb + hi);
                Oacc[0] = __builtin_amdgcn_mfma_f32_32x32x16_bf16(v0, f.b, Oacc[0], 0, 0, 0);
                Oacc[1] = __builtin_amdgcn_mfma_f32_32x32x16_bf16(v1, f.b, Oacc[1], 0, 0, 0);
            }
        __builtin_amdgcn_s_setprio(0);
    }

    // ---- combine the two s-halves through LDS (overlay on K/V pool) ----
    float lg = (lp[0] + lp[1]) + (lp[2] + lp[3]);
    lg += __shfl_xor(lg, 32);          // full half-sum for this t-column

    __syncthreads();                   // everyone done with K/V LDS
    const int qcol = qw * 32 + l31;    // 0..127
    if (gg == 1) {
#pragma unroll
        for (int cbk = 0; cbk < 2; ++cbk)
#pragma unroll
            for (int r = 0; r < 16; ++r) {
                const int c = cbk * 32 + (r & 3) + 8 * (r >> 2) + 4 * hi;
                comb[qcol * 65 + c] = Oacc[cbk][r];
            }
        if (hi == 0) combl[qcol] = lg;
    }
    __syncthreads();
    if (gg == 0) {
        const float rl = 1.0f / (lg + combl[qcol]);
#pragma unroll
        for (int cbk = 0; cbk < 2; ++cbk)
#pragma unroll
            for (int r = 0; r < 16; ++r) {
                const int c = cbk * 32 + (r & 3) + 8 * (r >> 2) + 4 * hi;
                const float o = Oacc[cbk][r] + comb[qcol * 65 + c];
                op[(size_t)c * SEQ + tq] = o * rl;
            }
    }
}

extern "C" void kernel_launch(void* const* d_in, const int* in_sizes, int n_in,
                              void* d_out, int out_size, void* d_ws, size_t ws_size,
                              hipStream_t stream) {
    const float* qkv = (const float*)d_in[0];
    float* out = (float*)d_out;
    __bf16* KT = (__bf16*)d_ws;                         // [32][2048][64] bf16
    __bf16* Vb = KT + (size_t)NHEADS * SEQ * DD;        // [32][64][2048] bf16
    prep_kernel<<<dim3(256 + 512), dim3(256), 0, stream>>>(qkv, KT, Vb);
    attn_kernel<<<dim3(NHEADS * (SEQ / QBLK)), dim3(NTHR), 0, stream>>>(qkv, KT, Vb, out);
}

// Round 17
// 57.546 us; speedup vs baseline: 2.6016x; 2.6016x over previous
//
#include <hip/hip_runtime.h>

// QKV attention, N=4 H=8 C=64 T=2048, fp32 in/out, bf16 MFMA internally.
// R17: R16's STR=68 padding zeroed the bank conflicts but its 136B row
// stride put odd rows at 8 mod 16 — misaligned b128 DS ops hit a ~3x slow
// path (R5/R6 were safe at STR=68 only because they used 8B accesses).
// Single change: STR=72 (144B rows = 16B-aligned, 36 banks). Bank math:
// read start = 4*(l31+c16) mod 32, write start = 4*(sr+sp) mod 32 -> both
// uniform 8 words/bank = the b128 minimum (conflict-free) AND aligned.
// LDS 72KB/block; 2 blocks x 72KB = 144KB <= 160KB/CU (co-residency kept).
// Rest identical to R16/R12: s-split 8-wave blocks, cvt_pk, permlane,
// mid-iteration vmcnt(0)+publish+barrier, XCD swizzle, bf16 K/V prep.

typedef __bf16 bf8v __attribute__((ext_vector_type(8)));
typedef float f16v __attribute__((ext_vector_type(16)));
typedef int i4 __attribute__((ext_vector_type(4)));

#define SEQ 2048
#define DD 64
#define NHEADS 32
#define QBLK 128
#define SBLK 64
#define NTILES 32             // s-tiles total; 16 per s-group
#define TILEK (SBLK * DD)     // elements per K/V source tile (4096)
#define STR 72                // padded LDS row stride in bf16 (144 B, 16B-aligned)
#define TILEE (SBLK * STR)    // elements per padded LDS tile (4608 = 9216 B)
#define NTHR 512

// scale = 1/sqrt(sqrt(64)) on both q and k; log2(e) folded into q's side
#define KSC 0.35355339059327373f
#define QSC (0.35355339059327373f * 1.4426950408889634f)

#if __has_builtin(__builtin_amdgcn_exp2f)
#define EXP2(x) __builtin_amdgcn_exp2f(x)
#else
#define EXP2(x) exp2f(x)
#endif

__device__ __forceinline__ void gload16(i4& dst, const void* p) {
    asm volatile("global_load_dwordx4 %0, %1, off" : "=&v"(dst) : "v"(p));
}

#define SBAR() __builtin_amdgcn_sched_barrier(0)
// drain-all: correct regardless of compiler-inserted vmem ops (spill-safe)
#define VMWAIT0() do { asm volatile("s_waitcnt vmcnt(0)" ::: "memory"); SBAR(); } while (0)

// packed f32->bf16 convert (T12 recipe, learn_hip-verified)
__device__ __forceinline__ unsigned cvtpk(float a, float b) {
    unsigned r;
    asm("v_cvt_pk_bf16_f32 %0, %1, %2" : "=v"(r) : "v"(a), "v"(b));
    return r;
}

// hi-half lane exchange (verified R8): a = {a_lo, b_lo'}, b = {a_hi', b_hi}
#if __has_builtin(__builtin_amdgcn_permlane32_swap)
typedef int i2v __attribute__((ext_vector_type(2)));
__device__ __forceinline__ void plswap(unsigned& a, unsigned& b) {
    i2v r = __builtin_amdgcn_permlane32_swap((int)a, (int)b, false, false);
    a = (unsigned)r.x;
    b = (unsigned)r.y;
}
#else
__device__ __forceinline__ void plswap(unsigned& a, unsigned& b) {
    asm volatile("v_permlane32_swap_b32 %0, %1" : "+v"(a), "+v"(b));
}
#endif

// ---------------- prep: fp32 -> bf16, K transposed+scaled, V straight --------
__global__ void prep_kernel(const float* __restrict__ qkv,
                            __bf16* __restrict__ KT, __bf16* __restrict__ Vb) {
    const int bx = blockIdx.x, tid = threadIdx.x;
    if (bx < 256) {
        const int head = bx >> 3, sblk = bx & 7;
        const int b = head >> 3, h = head & 7;
        const float* kp = qkv + (size_t)(b * 1536 + 512 + h * 64) * SEQ;
        __bf16* dst = KT + (size_t)head * SEQ * DD;
        const int s = sblk * 256 + tid;
#pragma unroll
        for (int c0 = 0; c0 < DD; c0 += 8) {
            bf8v v;
#pragma unroll
            for (int j = 0; j < 8; ++j)
                v[j] = (__bf16)(kp[(size_t)(c0 + j) * SEQ + s] * KSC);
            *(bf8v*)(dst + (size_t)s * DD + c0) = v;
        }
    } else {
        const int job = bx - 256;
        const int head = job >> 4, part = job & 15;
        const int b = head >> 3, h = head & 7;
        const float* vp = qkv + (size_t)(b * 1536 + 1024 + h * 64) * SEQ;
        __bf16* dst = Vb + (size_t)head * DD * SEQ;
#pragma unroll
        for (int i = 0; i < 4; ++i) {
            const int e = part * 8192 + (i * 256 + tid) * 8;
            const float4* f = (const float4*)(vp + e);
            float4 a = f[0], c = f[1];
            bf8v o;
            o[0] = (__bf16)a.x; o[1] = (__bf16)a.y; o[2] = (__bf16)a.z; o[3] = (__bf16)a.w;
            o[4] = (__bf16)c.x; o[5] = (__bf16)c.y; o[6] = (__bf16)c.z; o[7] = (__bf16)c.w;
            *(bf8v*)(dst + e) = o;
        }
    }
}

// padded LDS fragment read: row r (stride STR elem = 144 B), 16B chunk c16
__device__ __forceinline__ bf8v ldpad(const __bf16* base, int r, int c16) {
    return *(const bf8v*)(base + r * STR + ((c16) << 3));
}

__global__ __launch_bounds__(NTHR, 4) void attn_kernel(
    const float* __restrict__ qkv, const __bf16* __restrict__ KT,
    const __bf16* __restrict__ Vb, float* __restrict__ out)
{
    // 72KB pool: padded K/V tiles (2 grp x dbuf); combine overlays it.
    __shared__ __align__(16) char pool[4 * TILEE * 2 * 2];   // 73728 B
    __bf16* KLg = (__bf16*)pool;                       // [grp*2+buf][TILEE]
    __bf16* VLg = (__bf16*)(pool + 4 * TILEE * 2);     // [grp*2+buf][TILEE]
    float* comb  = (float*)pool;                       // [128][65] fp32 overlay
    float* combl = (float*)(pool + 33280);             // [128] fp32

    const int tid = threadIdx.x;
    const int wid = tid >> 6;
    const int gg  = wid >> 2;          // s-group 0/1
    const int qw  = wid & 3;           // q-wave within group
    const int lane = tid & 63;
    const int hi = lane >> 5;
    const int l31 = lane & 31;

    // XCD-bijective swizzle: 512 blocks, 8 XCDs -> 64-block chunks = 4 heads/XCD
    const int bid = blockIdx.x;
    const int bx = (bid & 7) * 64 + (bid >> 3);
    const int head = bx >> 4;
    const int t0 = (bx & 15) * QBLK;
    const int b = head >> 3, h = head & 7;

    const float* qp = qkv + (size_t)(b * 1536 + h * 64) * SEQ;
    const __bf16* kt = KT + (size_t)head * SEQ * DD;
    const __bf16* vb = Vb + (size_t)head * DD * SEQ;
    float* op = out + (size_t)head * DD * SEQ;

    // ---- staging geometry (per s-group: 256 threads cover the 64-row tile) --
    // linear source chunk; padded LDS dest row stride STR (16B-aligned rows)
    const int g256 = tid & 255;
    const int sp  = g256 & 7;          // 16B-chunk position within row
    const int sr  = g256 >> 3;         // 0..31
    const __bf16* kg0 = kt + sr * DD + (sp << 3);
    const __bf16* kg1 = kt + (sr + 32) * DD + (sp << 3);
    const __bf16* vg0 = vb + (size_t)sr * SEQ + (sp << 3);
    const __bf16* vg1 = vb + (size_t)(sr + 32) * SEQ + (sp << 3);
    const int l0 = sr * STR + (sp << 3);
    const int l1 = (sr + 32) * STR + (sp << 3);

    i4 rk0, rk1, rv0, rv1;

    // ---- prologue: issue group's tile(gg) loads; Q convert overlaps flight --
    SBAR();
    gload16(rk0, kg0 + gg * TILEK);
    gload16(rk1, kg1 + gg * TILEK);
    gload16(rv0, vg0 + gg * SBLK);
    gload16(rv1, vg1 + gg * SBLK);
    SBAR();

    // Q B-fragments for 32x32x16: col = t = l31, k = c = kb*16 + hi*8 + j
    const int tq = t0 + qw * 32 + l31;
    bf8v qf[4];
#pragma unroll
    for (int kb = 0; kb < 4; ++kb) {
        bf8v q;
#pragma unroll
        for (int j = 0; j < 8; ++j)
            q[j] = (__bf16)(qp[(size_t)(kb * 16 + hi * 8 + j) * SEQ + tq] * QSC);
        qf[kb] = q;
    }

    f16v Oacc[2];
    Oacc[0] = (f16v)0.0f;
    Oacc[1] = (f16v)0.0f;
    float lp[4] = {0.f, 0.f, 0.f, 0.f};

    VMWAIT0();
    {
        __bf16* k0 = KLg + (2 * gg) * TILEE;
        __bf16* v0 = VLg + (2 * gg) * TILEE;
        *(i4*)&k0[l0] = rk0;  *(i4*)&k0[l1] = rk1;
        *(i4*)&v0[l0] = rv0;  *(i4*)&v0[l1] = rv1;
    }
    __syncthreads();

    // ---- main loop: 16 iterations, group gg computes tiles 2*it+gg ----
    for (int it = 0; it < NTILES / 2; ++it) {
        const int cb = it & 1;
        const __bf16* kcu = KLg + (2 * gg + cb) * TILEE;
        const __bf16* vcu = VLg + (2 * gg + cb) * TILEE;
        const bool more = (it + 1 < NTILES / 2);

        // pinned issue of the group's next tile; latency hides under compute
        if (more) {
            const int tg = 2 * (it + 1) + gg;
            SBAR();
            gload16(rk0, kg0 + tg * TILEK);
            gload16(rk1, kg1 + tg * TILEK);
            gload16(rv0, vg0 + tg * SBLK);
            gload16(rv1, vg1 + tg * SBLK);
            SBAR();
        }

        // ---- QK^T + softmax, sequential over sb (caps live regs: one S) ----
        // S^T rows s = sb*32 + (reg&3) + 8*(reg>>2) + 4*hi, col t = l31
        unsigned pd[2][4][2];
#pragma unroll
        for (int sb = 0; sb < 2; ++sb) {
            f16v S = (f16v)0.0f;
            __builtin_amdgcn_s_setprio(1);
#pragma unroll
            for (int kb = 0; kb < 4; ++kb) {
                bf8v a = ldpad(kcu, sb * 32 + l31, 2 * kb + hi);
                S = __builtin_amdgcn_mfma_f32_32x32x16_bf16(a, qf[kb], S, 0, 0, 0);
            }
            __builtin_amdgcn_s_setprio(0);

            // exps via hazard-safe builtin; sums in f32; bf16 pack via cvt_pk
#pragma unroll
            for (int q = 0; q < 4; ++q) {
                float e0 = EXP2(S[4 * q + 0]);
                float e1 = EXP2(S[4 * q + 1]);
                float e2 = EXP2(S[4 * q + 2]);
                float e3 = EXP2(S[4 * q + 3]);
                lp[q] += (e0 + e1) + (e2 + e3);
                pd[sb][q][0] = cvtpk(e0, e1);
                pd[sb][q][1] = cvtpk(e2, e3);
            }
        }

        // hi-half exchange -> complete PV B-frags in-register
#pragma unroll
        for (int sb = 0; sb < 2; ++sb)
#pragma unroll
            for (int m = 0; m < 2; ++m) {
                plswap(pd[sb][2 * m][0], pd[sb][2 * m + 1][0]);
                plswap(pd[sb][2 * m][1], pd[sb][2 * m + 1][1]);
            }

        // ---- mid-iteration sync: land next tile, publish to buf^1, barrier --
        if (more) {
            VMWAIT0();
            __bf16* kn = KLg + (2 * gg + (cb ^ 1)) * TILEE;
            __bf16* vn = VLg + (2 * gg + (cb ^ 1)) * TILEE;
            *(i4*)&kn[l0] = rk0;  *(i4*)&kn[l1] = rk1;
            *(i4*)&vn[l0] = rv0;  *(i4*)&vn[l1] = rv1;
            __syncthreads();
        }

        // VALU(permlane)->MFMA-read hazard guard for the no-barrier last iter
        asm volatile("s_nop 2" :::);

        // ---- PV: O[c][t] += V[c][s] P^T[s][t]; V frags loaded per-kb ----
        __builtin_amdgcn_s_setprio(1);
#pragma unroll
        for (int sb = 0; sb < 2; ++sb)
#pragma unroll
            for (int m = 0; m < 2; ++m) {
                const int kb = 2 * sb + m;
                union { unsigned u[4]; bf8v b; } f;
                f.u[0] = pd[sb][2 * m][0];
                f.u[1] = pd[sb][2 * m][1];
                f.u[2] = pd[sb][2 * m + 1][0];
                f.u[3] = pd[sb][2 * m + 1][1];
                bf8v v0 = ldpad(vcu, l31,      2 * kb + hi);
                bf8v v1 = ldpad(vcu, 32 + l31, 2 * kb + hi);
                Oacc[0] = __builtin_amdgcn_mfma_f32_32x32x16_bf16(v0, f.b, Oacc[0], 0, 0, 0);
                Oacc[1] = __builtin_amdgcn_mfma_f32_32x32x16_bf16(v1, f.b, Oacc[1], 0, 0, 0);
            }
        __builtin_amdgcn_s_setprio(0);
    }

    // ---- combine the two s-halves through LDS (overlay on K/V pool) ----
    float lg = (lp[0] + lp[1]) + (lp[2] + lp[3]);
    lg += __shfl_xor(lg, 32);          // full half-sum for this t-column

    __syncthreads();                   // everyone done with K/V LDS
    const int qcol = qw * 32 + l31;    // 0..127
    if (gg == 1) {
#pragma unroll
        for (int cbk = 0; cbk < 2; ++cbk)
#pragma unroll
            for (int r = 0; r < 16; ++r) {
                const int c = cbk * 32 + (r & 3) + 8 * (r >> 2) + 4 * hi;
                comb[qcol * 65 + c] = Oacc[cbk][r];
            }
        if (hi == 0) combl[qcol] = lg;
    }
    __syncthreads();
    if (gg == 0) {
        const float rl = 1.0f / (lg + combl[qcol]);
#pragma unroll
        for (int cbk = 0; cbk < 2; ++cbk)
#pragma unroll
            for (int r = 0; r < 16; ++r) {
                const int c = cbk * 32 + (r & 3) + 8 * (r >> 2) + 4 * hi;
                const float o = Oacc[cbk][r] + comb[qcol * 65 + c];
                op[(size_t)c * SEQ + tq] = o * rl;
            }
    }
}

extern "C" void kernel_launch(void* const* d_in, const int* in_sizes, int n_in,
                              void* d_out, int out_size, void* d_ws, size_t ws_size,
                              hipStream_t stream) {
    const float* qkv = (const float*)d_in[0];
    float* out = (float*)d_out;
    __bf16* KT = (__bf16*)d_ws;                         // [32][2048][64] bf16
    __bf16* Vb = KT + (size_t)NHEADS * SEQ * DD;        // [32][64][2048] bf16
    prep_kernel<<<dim3(256 + 512), dim3(256), 0, stream>>>(qkv, KT, Vb);
    attn_kernel<<<dim3(NHEADS * (SEQ / QBLK)), dim3(NTHR), 0, stream>>>(qkv, KT, Vb, out);
}

// Round 18
// 57.235 us; speedup vs baseline: 2.6158x; 1.0054x over previous
//
#include <hip/hip_runtime.h>

// QKV attention, N=4 H=8 C=64 T=2048, fp32 in/out, bf16 MFMA internally.
// R18: R17 (best: 57.5us; STR=72 conflict-free aligned LDS) with ONE change:
// the vmcnt(0)+publish+barrier moves from between softmax and PV to AFTER PV
// (R14's ordering — race-free: PV reads buf cb, publish writes cb^1; next
// iteration's write of cb is behind this iteration's trailing barrier).
// Effect: prefetch latency window extends over PV, and the drain leaves the
// softmax->PV serial chain. Same one barrier + one drain-all per iteration;
// asm load outputs still consumed only by memory ops after vmcnt(0).

typedef __bf16 bf8v __attribute__((ext_vector_type(8)));
typedef float f16v __attribute__((ext_vector_type(16)));
typedef int i4 __attribute__((ext_vector_type(4)));

#define SEQ 2048
#define DD 64
#define NHEADS 32
#define QBLK 128
#define SBLK 64
#define NTILES 32             // s-tiles total; 16 per s-group
#define TILEK (SBLK * DD)     // elements per K/V source tile (4096)
#define STR 72                // padded LDS row stride in bf16 (144 B, 16B-aligned)
#define TILEE (SBLK * STR)    // elements per padded LDS tile (4608 = 9216 B)
#define NTHR 512

// scale = 1/sqrt(sqrt(64)) on both q and k; log2(e) folded into q's side
#define KSC 0.35355339059327373f
#define QSC (0.35355339059327373f * 1.4426950408889634f)

#if __has_builtin(__builtin_amdgcn_exp2f)
#define EXP2(x) __builtin_amdgcn_exp2f(x)
#else
#define EXP2(x) exp2f(x)
#endif

__device__ __forceinline__ void gload16(i4& dst, const void* p) {
    asm volatile("global_load_dwordx4 %0, %1, off" : "=&v"(dst) : "v"(p));
}

#define SBAR() __builtin_amdgcn_sched_barrier(0)
// drain-all: correct regardless of compiler-inserted vmem ops (spill-safe)
#define VMWAIT0() do { asm volatile("s_waitcnt vmcnt(0)" ::: "memory"); SBAR(); } while (0)

// packed f32->bf16 convert (T12 recipe, learn_hip-verified)
__device__ __forceinline__ unsigned cvtpk(float a, float b) {
    unsigned r;
    asm("v_cvt_pk_bf16_f32 %0, %1, %2" : "=v"(r) : "v"(a), "v"(b));
    return r;
}

// hi-half lane exchange (verified R8): a = {a_lo, b_lo'}, b = {a_hi', b_hi}
#if __has_builtin(__builtin_amdgcn_permlane32_swap)
typedef int i2v __attribute__((ext_vector_type(2)));
__device__ __forceinline__ void plswap(unsigned& a, unsigned& b) {
    i2v r = __builtin_amdgcn_permlane32_swap((int)a, (int)b, false, false);
    a = (unsigned)r.x;
    b = (unsigned)r.y;
}
#else
__device__ __forceinline__ void plswap(unsigned& a, unsigned& b) {
    asm volatile("v_permlane32_swap_b32 %0, %1" : "+v"(a), "+v"(b));
}
#endif

// ---------------- prep: fp32 -> bf16, K transposed+scaled, V straight --------
__global__ void prep_kernel(const float* __restrict__ qkv,
                            __bf16* __restrict__ KT, __bf16* __restrict__ Vb) {
    const int bx = blockIdx.x, tid = threadIdx.x;
    if (bx < 256) {
        const int head = bx >> 3, sblk = bx & 7;
        const int b = head >> 3, h = head & 7;
        const float* kp = qkv + (size_t)(b * 1536 + 512 + h * 64) * SEQ;
        __bf16* dst = KT + (size_t)head * SEQ * DD;
        const int s = sblk * 256 + tid;
#pragma unroll
        for (int c0 = 0; c0 < DD; c0 += 8) {
            bf8v v;
#pragma unroll
            for (int j = 0; j < 8; ++j)
                v[j] = (__bf16)(kp[(size_t)(c0 + j) * SEQ + s] * KSC);
            *(bf8v*)(dst + (size_t)s * DD + c0) = v;
        }
    } else {
        const int job = bx - 256;
        const int head = job >> 4, part = job & 15;
        const int b = head >> 3, h = head & 7;
        const float* vp = qkv + (size_t)(b * 1536 + 1024 + h * 64) * SEQ;
        __bf16* dst = Vb + (size_t)head * DD * SEQ;
#pragma unroll
        for (int i = 0; i < 4; ++i) {
            const int e = part * 8192 + (i * 256 + tid) * 8;
            const float4* f = (const float4*)(vp + e);
            float4 a = f[0], c = f[1];
            bf8v o;
            o[0] = (__bf16)a.x; o[1] = (__bf16)a.y; o[2] = (__bf16)a.z; o[3] = (__bf16)a.w;
            o[4] = (__bf16)c.x; o[5] = (__bf16)c.y; o[6] = (__bf16)c.z; o[7] = (__bf16)c.w;
            *(bf8v*)(dst + e) = o;
        }
    }
}

// padded LDS fragment read: row r (stride STR elem = 144 B), 16B chunk c16
__device__ __forceinline__ bf8v ldpad(const __bf16* base, int r, int c16) {
    return *(const bf8v*)(base + r * STR + ((c16) << 3));
}

__global__ __launch_bounds__(NTHR, 4) void attn_kernel(
    const float* __restrict__ qkv, const __bf16* __restrict__ KT,
    const __bf16* __restrict__ Vb, float* __restrict__ out)
{
    // 72KB pool: padded K/V tiles (2 grp x dbuf); combine overlays it.
    __shared__ __align__(16) char pool[4 * TILEE * 2 * 2];   // 73728 B
    __bf16* KLg = (__bf16*)pool;                       // [grp*2+buf][TILEE]
    __bf16* VLg = (__bf16*)(pool + 4 * TILEE * 2);     // [grp*2+buf][TILEE]
    float* comb  = (float*)pool;                       // [128][65] fp32 overlay
    float* combl = (float*)(pool + 33280);             // [128] fp32

    const int tid = threadIdx.x;
    const int wid = tid >> 6;
    const int gg  = wid >> 2;          // s-group 0/1
    const int qw  = wid & 3;           // q-wave within group
    const int lane = tid & 63;
    const int hi = lane >> 5;
    const int l31 = lane & 31;

    // XCD-bijective swizzle: 512 blocks, 8 XCDs -> 64-block chunks = 4 heads/XCD
    const int bid = blockIdx.x;
    const int bx = (bid & 7) * 64 + (bid >> 3);
    const int head = bx >> 4;
    const int t0 = (bx & 15) * QBLK;
    const int b = head >> 3, h = head & 7;

    const float* qp = qkv + (size_t)(b * 1536 + h * 64) * SEQ;
    const __bf16* kt = KT + (size_t)head * SEQ * DD;
    const __bf16* vb = Vb + (size_t)head * DD * SEQ;
    float* op = out + (size_t)head * DD * SEQ;

    // ---- staging geometry (per s-group: 256 threads cover the 64-row tile) --
    // linear source chunk; padded LDS dest row stride STR (16B-aligned rows)
    const int g256 = tid & 255;
    const int sp  = g256 & 7;          // 16B-chunk position within row
    const int sr  = g256 >> 3;         // 0..31
    const __bf16* kg0 = kt + sr * DD + (sp << 3);
    const __bf16* kg1 = kt + (sr + 32) * DD + (sp << 3);
    const __bf16* vg0 = vb + (size_t)sr * SEQ + (sp << 3);
    const __bf16* vg1 = vb + (size_t)(sr + 32) * SEQ + (sp << 3);
    const int l0 = sr * STR + (sp << 3);
    const int l1 = (sr + 32) * STR + (sp << 3);

    i4 rk0, rk1, rv0, rv1;

    // ---- prologue: issue group's tile(gg) loads; Q convert overlaps flight --
    SBAR();
    gload16(rk0, kg0 + gg * TILEK);
    gload16(rk1, kg1 + gg * TILEK);
    gload16(rv0, vg0 + gg * SBLK);
    gload16(rv1, vg1 + gg * SBLK);
    SBAR();

    // Q B-fragments for 32x32x16: col = t = l31, k = c = kb*16 + hi*8 + j
    const int tq = t0 + qw * 32 + l31;
    bf8v qf[4];
#pragma unroll
    for (int kb = 0; kb < 4; ++kb) {
        bf8v q;
#pragma unroll
        for (int j = 0; j < 8; ++j)
            q[j] = (__bf16)(qp[(size_t)(kb * 16 + hi * 8 + j) * SEQ + tq] * QSC);
        qf[kb] = q;
    }

    f16v Oacc[2];
    Oacc[0] = (f16v)0.0f;
    Oacc[1] = (f16v)0.0f;
    float lp[4] = {0.f, 0.f, 0.f, 0.f};

    VMWAIT0();
    {
        __bf16* k0 = KLg + (2 * gg) * TILEE;
        __bf16* v0 = VLg + (2 * gg) * TILEE;
        *(i4*)&k0[l0] = rk0;  *(i4*)&k0[l1] = rk1;
        *(i4*)&v0[l0] = rv0;  *(i4*)&v0[l1] = rv1;
    }
    __syncthreads();

    // ---- main loop: 16 iterations, group gg computes tiles 2*it+gg ----
    for (int it = 0; it < NTILES / 2; ++it) {
        const int cb = it & 1;
        const __bf16* kcu = KLg + (2 * gg + cb) * TILEE;
        const __bf16* vcu = VLg + (2 * gg + cb) * TILEE;
        const bool more = (it + 1 < NTILES / 2);

        // pinned issue of the group's next tile; latency window now spans
        // QK + softmax + plswap + PV (drained only after PV)
        if (more) {
            const int tg = 2 * (it + 1) + gg;
            SBAR();
            gload16(rk0, kg0 + tg * TILEK);
            gload16(rk1, kg1 + tg * TILEK);
            gload16(rv0, vg0 + tg * SBLK);
            gload16(rv1, vg1 + tg * SBLK);
            SBAR();
        }

        // ---- QK^T + softmax, sequential over sb (caps live regs: one S) ----
        // S^T rows s = sb*32 + (reg&3) + 8*(reg>>2) + 4*hi, col t = l31
        unsigned pd[2][4][2];
#pragma unroll
        for (int sb = 0; sb < 2; ++sb) {
            f16v S = (f16v)0.0f;
            __builtin_amdgcn_s_setprio(1);
#pragma unroll
            for (int kb = 0; kb < 4; ++kb) {
                bf8v a = ldpad(kcu, sb * 32 + l31, 2 * kb + hi);
                S = __builtin_amdgcn_mfma_f32_32x32x16_bf16(a, qf[kb], S, 0, 0, 0);
            }
            __builtin_amdgcn_s_setprio(0);

            // exps via hazard-safe builtin; sums in f32; bf16 pack via cvt_pk
#pragma unroll
            for (int q = 0; q < 4; ++q) {
                float e0 = EXP2(S[4 * q + 0]);
                float e1 = EXP2(S[4 * q + 1]);
                float e2 = EXP2(S[4 * q + 2]);
                float e3 = EXP2(S[4 * q + 3]);
                lp[q] += (e0 + e1) + (e2 + e3);
                pd[sb][q][0] = cvtpk(e0, e1);
                pd[sb][q][1] = cvtpk(e2, e3);
            }
        }

        // hi-half exchange -> complete PV B-frags in-register
#pragma unroll
        for (int sb = 0; sb < 2; ++sb)
#pragma unroll
            for (int m = 0; m < 2; ++m) {
                plswap(pd[sb][2 * m][0], pd[sb][2 * m + 1][0]);
                plswap(pd[sb][2 * m][1], pd[sb][2 * m + 1][1]);
            }

        // VALU(permlane)->MFMA-read hazard guard
        asm volatile("s_nop 2" :::);

        // ---- PV: O[c][t] += V[c][s] P^T[s][t]; V frags from LDS buf cb ----
        __builtin_amdgcn_s_setprio(1);
#pragma unroll
        for (int sb = 0; sb < 2; ++sb)
#pragma unroll
            for (int m = 0; m < 2; ++m) {
                const int kb = 2 * sb + m;
                union { unsigned u[4]; bf8v b; } f;
                f.u[0] = pd[sb][2 * m][0];
                f.u[1] = pd[sb][2 * m][1];
                f.u[2] = pd[sb][2 * m + 1][0];
                f.u[3] = pd[sb][2 * m + 1][1];
                bf8v v0 = ldpad(vcu, l31,      2 * kb + hi);
                bf8v v1 = ldpad(vcu, 32 + l31, 2 * kb + hi);
                Oacc[0] = __builtin_amdgcn_mfma_f32_32x32x16_bf16(v0, f.b, Oacc[0], 0, 0, 0);
                Oacc[1] = __builtin_amdgcn_mfma_f32_32x32x16_bf16(v1, f.b, Oacc[1], 0, 0, 0);
            }
        __builtin_amdgcn_s_setprio(0);

        // ---- single drain + publish + barrier, AFTER PV (race-free:
        //      PV read buf cb; publish writes cb^1; next write of cb is
        //      behind this barrier via iteration it+1's trailing barrier) ----
        if (more) {
            VMWAIT0();
            __bf16* kn = KLg + (2 * gg + (cb ^ 1)) * TILEE;
            __bf16* vn = VLg + (2 * gg + (cb ^ 1)) * TILEE;
            *(i4*)&kn[l0] = rk0;  *(i4*)&kn[l1] = rk1;
            *(i4*)&vn[l0] = rv0;  *(i4*)&vn[l1] = rv1;
            __syncthreads();
        }
    }

    // ---- combine the two s-halves through LDS (overlay on K/V pool) ----
    float lg = (lp[0] + lp[1]) + (lp[2] + lp[3]);
    lg += __shfl_xor(lg, 32);          // full half-sum for this t-column

    __syncthreads();                   // everyone done with K/V LDS
    const int qcol = qw * 32 + l31;    // 0..127
    if (gg == 1) {
#pragma unroll
        for (int cbk = 0; cbk < 2; ++cbk)
#pragma unroll
            for (int r = 0; r < 16; ++r) {
                const int c = cbk * 32 + (r & 3) + 8 * (r >> 2) + 4 * hi;
                comb[qcol * 65 + c] = Oacc[cbk][r];
            }
        if (hi == 0) combl[qcol] = lg;
    }
    __syncthreads();
    if (gg == 0) {
        const float rl = 1.0f / (lg + combl[qcol]);
#pragma unroll
        for (int cbk = 0; cbk < 2; ++cbk)
#pragma unroll
            for (int r = 0; r < 16; ++r) {
                const int c = cbk * 32 + (r & 3) + 8 * (r >> 2) + 4 * hi;
                const float o = Oacc[cbk][r] + comb[qcol * 65 + c];
                op[(size_t)c * SEQ + tq] = o * rl;
            }
    }
}

extern "C" void kernel_launch(void* const* d_in, const int* in_sizes, int n_in,
                              void* d_out, int out_size, void* d_ws, size_t ws_size,
                              hipStream_t stream) {
    const float* qkv = (const float*)d_in[0];
    float* out = (float*)d_out;
    __bf16* KT = (__bf16*)d_ws;                         // [32][2048][64] bf16
    __bf16* Vb = KT + (size_t)NHEADS * SEQ * DD;        // [32][64][2048] bf16
    prep_kernel<<<dim3(256 + 512), dim3(256), 0, stream>>>(qkv, KT, Vb);
    attn_kernel<<<dim3(NHEADS * (SEQ / QBLK)), dim3(NTHR), 0, stream>>>(qkv, KT, Vb, out);
}